// Round 10
// baseline (160.426 us; speedup 1.0000x reference)
//
#include <hip/hip_runtime.h>

#define NPTS 8192
#define DIM 64
#define EPSF 1e-7f
#define LN2F 0.69314718055994531f
#define NBLK 1056   // sum_{by=0}^{31} (64 - 2*by)

typedef unsigned short u16;
typedef __attribute__((ext_vector_type(8))) short bf16x8;   // 8 bf16 (4 VGPRs)
typedef __attribute__((ext_vector_type(8))) unsigned short u16x8;
typedef __attribute__((ext_vector_type(4))) float f32x4;

// ---- kernel 1: split x into bf16 hi/lo; hsq=-sq/2, rcpom=1/(1-sq), m4r=-4/(1-sq)
// Also zeroes S, T, out (replaces the memset dispatch).
__global__ void prep_kernel(const float* __restrict__ x,
                            u16* __restrict__ hi, u16* __restrict__ lo,
                            float* __restrict__ hsq, float* __restrict__ rcpom,
                            float* __restrict__ m4r,
                            float* __restrict__ S, float* __restrict__ T,
                            float* __restrict__ out) {
    int g = blockIdx.x * blockDim.x + threadIdx.x;   // 0 .. NPTS*8-1
    int row = g >> 3, sub = g & 7;
    const float* xp = x + row * DIM + sub * 8;
    float v[8];
    float s = 0.f;
#pragma unroll
    for (int k = 0; k < 8; k++) { v[k] = xp[k]; s = fmaf(v[k], v[k], s); }
    s += __shfl_xor(s, 1);
    s += __shfl_xor(s, 2);
    s += __shfl_xor(s, 4);
    u16x8 h, l;
#pragma unroll
    for (int k = 0; k < 8; k++) {
        unsigned int bits = __float_as_uint(v[k]);
        u16 hb = (u16)(bits >> 16);                       // truncation: hi exact bf16
        float hf = __uint_as_float(((unsigned int)hb) << 16);
        float lf = v[k] - hf;                             // exact in fp32
        u16 lb = (u16)(__float_as_uint(lf) >> 16);
        h[k] = hb; l[k] = lb;
    }
    *(u16x8*)(hi + row * DIM + sub * 8) = h;
    *(u16x8*)(lo + row * DIM + sub * 8) = l;
    if (sub == 0) {
        float r = 1.0f / (1.0f - s);
        hsq[row] = -0.5f * s;
        rcpom[row] = r;
        m4r[row] = -4.0f * r;
    } else if (sub == 1) {
        S[row] = 0.f;
    } else if (sub == 2) {
        T[row] = 0.f;
    }
    if (g == 3) out[0] = 0.f;
}

// C(b) = number of active tiles with by < b
__device__ __forceinline__ int cumtiles(int b) { return 65 * b - b * b; }

// ---- kernel 2: triangular fused MFMA Gram + hyperbolic epilogue -------------
// 1056 active tiles: block tile 128(i) x 256(j), active iff bx >= 2*by.
// Straddle tiles (off<2) do i-side only; full tiles accumulate each pair to
// BOTH row i (regs) and row j (per-wave LDS slab, one flush per block).
// launch_bounds(256,4): 1056 blocks / 4-per-CU ~= one scheduling round (R9's
// (256,3) left a 2-round tail: occupancy 21%). B frags double-buffered in
// registers across t to hide the L1/L2 load latency behind MFMA+epilogue.
__global__ void __launch_bounds__(256, 4) pair_mfma(
        const u16* __restrict__ hi, const u16* __restrict__ lo,
        const float* __restrict__ hsq, const float* __restrict__ rcpom,
        const float* __restrict__ m4r, const int* __restrict__ labels,
        float* __restrict__ Sarr, float* __restrict__ Tarr) {
    __shared__ float slabS[4][256], slabT[4][256];

    int tid = threadIdx.x;
    // invert linear block id -> (by, bx) in the triangular tile set
    int bid = blockIdx.x;
    int by = (int)((65.0f - __builtin_amdgcn_sqrtf(4225.0f - 4.0f * (float)bid)) * 0.5f);
    while (cumtiles(by + 1) <= bid) by++;
    while (cumtiles(by) > bid) by--;
    int off = bid - cumtiles(by);
    int bx = 2 * by + off;
    bool full = (off >= 2);

    int wave = tid >> 6, lane = tid & 63;
    int quad = lane >> 4, l15 = lane & 15;
    int i0 = bx * 128 + wave * 32;
    int j0 = by * 256;

    bf16x8 a_hi[2][2], a_lo[2][2];
#pragma unroll
    for (int it = 0; it < 2; it++)
#pragma unroll
        for (int ks = 0; ks < 2; ks++) {
            int aoff = (i0 + it * 16 + l15) * DIM + ks * 32 + quad * 8;
            a_hi[it][ks] = *(const bf16x8*)(hi + aoff);
            a_lo[it][ks] = *(const bf16x8*)(lo + aoff);
        }

    float hsqi[8], rcpi[8]; int labi[8];
#pragma unroll
    for (int it = 0; it < 2; it++)
#pragma unroll
        for (int r = 0; r < 4; r++) {
            int row = i0 + it * 16 + quad * 4 + r;
            hsqi[it * 4 + r] = hsq[row];
            rcpi[it * 4 + r] = rcpom[row];
            labi[it * 4 + r] = labels[row];
        }

    if (full) {
        slabS[wave][lane] = 0.f;       slabT[wave][lane] = 0.f;
        slabS[wave][lane + 64] = 0.f;  slabT[wave][lane + 64] = 0.f;
        slabS[wave][lane + 128] = 0.f; slabT[wave][lane + 128] = 0.f;
        slabS[wave][lane + 192] = 0.f; slabT[wave][lane + 192] = 0.f;
    }

    float Sx[8], Tx[8];
#pragma unroll
    for (int k = 0; k < 8; k++) { Sx[k] = 0.f; Tx[k] = 0.f; }

    // explicit register double-buffer for B fragments + per-j scalars
    bf16x8 bh[2][2], bl[2][2];
    float hsj[2], mj4[2]; int lbj[2];
    {
        int jg = j0 + l15;
        int boff = jg * DIM + quad * 8;
        bh[0][0] = *(const bf16x8*)(hi + boff);
        bh[0][1] = *(const bf16x8*)(hi + boff + 32);
        bl[0][0] = *(const bf16x8*)(lo + boff);
        bl[0][1] = *(const bf16x8*)(lo + boff + 32);
        hsj[0] = hsq[jg]; mj4[0] = m4r[jg]; lbj[0] = labels[jg];
    }

#pragma unroll 2
    for (int t = 0; t < 16; t++) {
        int cur = t & 1, nxt = cur ^ 1;
        if (t < 15) {
            int jg = j0 + (t + 1) * 16 + l15;
            int boff = jg * DIM + quad * 8;
            bh[nxt][0] = *(const bf16x8*)(hi + boff);
            bh[nxt][1] = *(const bf16x8*)(hi + boff + 32);
            bl[nxt][0] = *(const bf16x8*)(lo + boff);
            bl[nxt][1] = *(const bf16x8*)(lo + boff + 32);
            hsj[nxt] = hsq[jg]; mj4[nxt] = m4r[jg]; lbj[nxt] = labels[jg];
        }

        float pS = 0.f, pT = 0.f;
#pragma unroll
        for (int it = 0; it < 2; it++) {
            f32x4 acc0, acc1;
#pragma unroll
            for (int r = 0; r < 4; r++) { acc0[r] = hsqi[it * 4 + r] + hsj[cur]; acc1[r] = 0.f; }
            acc0 = __builtin_amdgcn_mfma_f32_16x16x32_bf16(a_lo[it][0], bh[cur][0], acc0, 0, 0, 0);
            acc1 = __builtin_amdgcn_mfma_f32_16x16x32_bf16(a_lo[it][1], bh[cur][1], acc1, 0, 0, 0);
            acc0 = __builtin_amdgcn_mfma_f32_16x16x32_bf16(a_hi[it][0], bl[cur][0], acc0, 0, 0, 0);
            acc1 = __builtin_amdgcn_mfma_f32_16x16x32_bf16(a_hi[it][1], bl[cur][1], acc1, 0, 0, 0);
            acc0 = __builtin_amdgcn_mfma_f32_16x16x32_bf16(a_hi[it][0], bh[cur][0], acc0, 0, 0, 0);
            acc1 = __builtin_amdgcn_mfma_f32_16x16x32_bf16(a_hi[it][1], bh[cur][1], acc1, 0, 0, 0);

#pragma unroll
            for (int r = 0; r < 4; r++) {
                int idx = it * 4 + r;
                float D = acc0[r] + acc1[r];                  // dot - (sqi+sqj)/2
                float u = fmaxf(D * rcpi[idx] * mj4[cur], EPSF);
                float srt = __builtin_amdgcn_sqrtf(fmaf(u, u, u + u));
                float opu = 1.0f + u;
                float st = opu - srt;                         // exp(-d)
                float l2 = __builtin_amdgcn_logf(opu + srt);  // d / ln2
                float tv = (lbj[cur] == labi[idx]) ? l2 : 0.0f;
                Sx[idx] += st;
                Tx[idx] += tv;
                pS += st; pT += tv;
            }
        }

        if (full) {
            // sum the 4 quads -> full 32-row partial for column jg
            pS += __shfl_xor(pS, 16); pS += __shfl_xor(pS, 32);
            pT += __shfl_xor(pT, 16); pT += __shfl_xor(pT, 32);
            if (quad == 0) {
                int c = t * 16 + l15;
                slabS[wave][c] += pS;
                slabT[wave][c] += pT;
            }
        }
    }

    // i-side: reduce across the 16 j-columns (lanes within a quad share rows)
#pragma unroll
    for (int r = 0; r < 8; r++) {
#pragma unroll
        for (int m = 1; m < 16; m <<= 1) {
            Sx[r] += __shfl_xor(Sx[r], m);
            Tx[r] += __shfl_xor(Tx[r], m);
        }
    }
    if (l15 == 0) {
#pragma unroll
        for (int it = 0; it < 2; it++)
#pragma unroll
            for (int r = 0; r < 4; r++) {
                int row = i0 + it * 16 + quad * 4 + r;
                atomicAdd(&Sarr[row], Sx[it * 4 + r]);
                atomicAdd(&Tarr[row], Tx[it * 4 + r]);
            }
    }

    // j-side: flush per-wave slabs (full tiles only; branch is block-uniform)
    if (full) {
        __syncthreads();
        float s = slabS[0][tid] + slabS[1][tid] + slabS[2][tid] + slabS[3][tid];
        float tt = slabT[0][tid] + slabT[1][tid] + slabT[2][tid] + slabT[3][tid];
        atomicAdd(&Sarr[j0 + tid], s);
        atomicAdd(&Tarr[j0 + tid], tt);
    }
}

// ---- kernel 3: finalize, 32 parallel blocks ---------------------------------
__global__ void __launch_bounds__(256) finalize_kernel(
        const float* __restrict__ S, const float* __restrict__ T,
        const int* __restrict__ labels, float* __restrict__ out) {
    __shared__ int hist[16][16];
    __shared__ float cntf[16];
    __shared__ float red[256];
    int tid = threadIdx.x;
    hist[tid >> 4][tid & 15] = 0;
    __syncthreads();
    int rep = tid & 15;
    for (int i = tid; i < NPTS; i += 256)
        atomicAdd(&hist[rep][labels[i]], 1);
    __syncthreads();
    if (tid < 16) {
        int s = 0;
#pragma unroll
        for (int k = 0; k < 16; k++) s += hist[k][tid];
        cntf[tid] = (float)(s - 1);
    }
    __syncthreads();

    float s0 = __builtin_amdgcn_sqrtf(EPSF * (2.0f + EPSF));
    float st0 = 1.0f + EPSF - s0;                         // self exp(-d) term
    float l20 = __builtin_amdgcn_logf(1.0f + EPSF + s0);  // self log2 term
    int i = blockIdx.x * 256 + tid;
    float loss = __logf(S[i] - st0) + (T[i] - l20) * LN2F / cntf[labels[i]];
    red[tid] = loss;
    __syncthreads();
    for (int s = 128; s > 0; s >>= 1) {
        if (tid < s) red[tid] += red[tid + s];
        __syncthreads();
    }
    if (tid == 0) atomicAdd(out, red[0]);
}

extern "C" void kernel_launch(void* const* d_in, const int* in_sizes, int n_in,
                              void* d_out, int out_size, void* d_ws, size_t ws_size,
                              hipStream_t stream) {
    const float* x = (const float*)d_in[0];
    const int* labels = (const int*)d_in[1];

    u16* hi = (u16*)d_ws;                 // NPTS*DIM u16
    u16* lo = hi + NPTS * DIM;            // NPTS*DIM u16
    float* hsq = (float*)(lo + NPTS * DIM);
    float* rcpom = hsq + NPTS;
    float* m4r = rcpom + NPTS;
    float* S = m4r + NPTS;
    float* T = S + NPTS;

    prep_kernel<<<(NPTS * 8) / 256, 256, 0, stream>>>(x, hi, lo, hsq, rcpom, m4r, S, T, (float*)d_out);

    pair_mfma<<<NBLK, 256, 0, stream>>>(hi, lo, hsq, rcpom, m4r, labels, S, T);

    finalize_kernel<<<NPTS / 256, 256, 0, stream>>>(S, T, labels, (float*)d_out);
}

// Round 11
// 136.374 us; speedup vs baseline: 1.1764x; 1.1764x over previous
//
#include <hip/hip_runtime.h>

#define NPTS 8192
#define DIM 64
#define EPSF 1e-7f
#define LN2F 0.69314718055994531f
#define NBLK 1056   // sum_{by=0}^{31} (64 - 2*by)
#define PERSISTENT 768  // 3 blocks/CU x 256 CU

typedef unsigned short u16;
typedef __attribute__((ext_vector_type(8))) short bf16x8;   // 8 bf16 (4 VGPRs)
typedef __attribute__((ext_vector_type(8))) unsigned short u16x8;
typedef __attribute__((ext_vector_type(4))) float f32x4;

// ---- kernel 1: split x into bf16 hi/lo; meta[row] = {-sq/2, 1/(1-sq), -4/(1-sq), label}
// Also zeroes S, T, out, tile counter.
__global__ void prep_kernel(const float* __restrict__ x, const int* __restrict__ labels,
                            u16* __restrict__ hi, u16* __restrict__ lo,
                            float4* __restrict__ meta,
                            float* __restrict__ S, float* __restrict__ T,
                            float* __restrict__ out, int* __restrict__ ctr) {
    int g = blockIdx.x * blockDim.x + threadIdx.x;   // 0 .. NPTS*8-1
    int row = g >> 3, sub = g & 7;
    const float* xp = x + row * DIM + sub * 8;
    float v[8];
    float s = 0.f;
#pragma unroll
    for (int k = 0; k < 8; k++) { v[k] = xp[k]; s = fmaf(v[k], v[k], s); }
    s += __shfl_xor(s, 1);
    s += __shfl_xor(s, 2);
    s += __shfl_xor(s, 4);
    u16x8 h, l;
#pragma unroll
    for (int k = 0; k < 8; k++) {
        unsigned int bits = __float_as_uint(v[k]);
        u16 hb = (u16)(bits >> 16);                       // truncation: hi exact bf16
        float hf = __uint_as_float(((unsigned int)hb) << 16);
        float lf = v[k] - hf;                             // exact in fp32
        u16 lb = (u16)(__float_as_uint(lf) >> 16);
        h[k] = hb; l[k] = lb;
    }
    *(u16x8*)(hi + row * DIM + sub * 8) = h;
    *(u16x8*)(lo + row * DIM + sub * 8) = l;
    if (sub == 0) {
        float r = 1.0f / (1.0f - s);
        meta[row] = make_float4(-0.5f * s, r, -4.0f * r, (float)labels[row]);
    } else if (sub == 1) {
        S[row] = 0.f;
    } else if (sub == 2) {
        T[row] = 0.f;
    }
    if (g == 3) { out[0] = 0.f; }
    if (g == 4) { *ctr = 0; }
}

// C(b) = number of active tiles with by < b
__device__ __forceinline__ int cumtiles(int b) { return 65 * b - b * b; }

// ---- kernel 2: persistent triangular fused MFMA Gram + hyperbolic epilogue --
// 1056 logical tiles, grabbed dynamically by 768 persistent blocks (3/CU):
// eliminates R9's 2-round tail (occ 21%). Tile: 128(i) x 256(j), active iff
// bx >= 2*by; straddle tiles (off<2) i-side only; full tiles also accumulate
// row j via per-wave LDS slab. No fences (R7 lesson); no register dbuf and
// launch_bounds(256,3) (R10 lesson: dbuf at (256,4) scratch-spills, 87MB).
__global__ void __launch_bounds__(256, 3) pair_mfma(
        const u16* __restrict__ hi, const u16* __restrict__ lo,
        const float4* __restrict__ meta,
        float* __restrict__ Sarr, float* __restrict__ Tarr,
        int* __restrict__ ctr) {
    __shared__ float slabS[4][256], slabT[4][256];
    __shared__ int curTile;

    int tid = threadIdx.x;
    int wave = tid >> 6, lane = tid & 63;
    int quad = lane >> 4, l15 = lane & 15;

    while (true) {
        if (tid == 0) curTile = atomicAdd(ctr, 1);
        __syncthreads();
        int bid = curTile;
        if (bid >= NBLK) break;                 // block-uniform exit

        // invert linear tile id -> (by, bx)
        int by = (int)((65.0f - __builtin_amdgcn_sqrtf(4225.0f - 4.0f * (float)bid)) * 0.5f);
        while (cumtiles(by + 1) <= bid) by++;
        while (cumtiles(by) > bid) by--;
        int off = bid - cumtiles(by);
        int bx = 2 * by + off;
        bool full = (off >= 2);

        int i0 = bx * 128 + wave * 32;
        int j0 = by * 256;

        bf16x8 a_hi[2][2], a_lo[2][2];
#pragma unroll
        for (int it = 0; it < 2; it++)
#pragma unroll
            for (int ks = 0; ks < 2; ks++) {
                int aoff = (i0 + it * 16 + l15) * DIM + ks * 32 + quad * 8;
                a_hi[it][ks] = *(const bf16x8*)(hi + aoff);
                a_lo[it][ks] = *(const bf16x8*)(lo + aoff);
            }

        float hsqi[8], rcpi[8], labi[8];
#pragma unroll
        for (int it = 0; it < 2; it++)
#pragma unroll
            for (int r = 0; r < 4; r++) {
                float4 m = meta[i0 + it * 16 + quad * 4 + r];
                hsqi[it * 4 + r] = m.x;
                rcpi[it * 4 + r] = m.y;
                labi[it * 4 + r] = m.w;
            }

        if (full) {
            slabS[wave][lane] = 0.f;       slabT[wave][lane] = 0.f;
            slabS[wave][lane + 64] = 0.f;  slabT[wave][lane + 64] = 0.f;
            slabS[wave][lane + 128] = 0.f; slabT[wave][lane + 128] = 0.f;
            slabS[wave][lane + 192] = 0.f; slabT[wave][lane + 192] = 0.f;
        }

        float Sx[8], Tx[8];
#pragma unroll
        for (int k = 0; k < 8; k++) { Sx[k] = 0.f; Tx[k] = 0.f; }

#pragma unroll 2
        for (int t = 0; t < 16; t++) {
            int jg = j0 + t * 16 + l15;
            bf16x8 b_hi[2], b_lo[2];
#pragma unroll
            for (int ks = 0; ks < 2; ks++) {
                int boff = jg * DIM + ks * 32 + quad * 8;
                b_hi[ks] = *(const bf16x8*)(hi + boff);
                b_lo[ks] = *(const bf16x8*)(lo + boff);
            }
            float4 mj = meta[jg];    // {hsqj, rcpomj, m4rj, labj}

            float pS = 0.f, pT = 0.f;
#pragma unroll
            for (int it = 0; it < 2; it++) {
                f32x4 acc0, acc1;
#pragma unroll
                for (int r = 0; r < 4; r++) { acc0[r] = hsqi[it * 4 + r] + mj.x; acc1[r] = 0.f; }
                acc0 = __builtin_amdgcn_mfma_f32_16x16x32_bf16(a_lo[it][0], b_hi[0], acc0, 0, 0, 0);
                acc1 = __builtin_amdgcn_mfma_f32_16x16x32_bf16(a_lo[it][1], b_hi[1], acc1, 0, 0, 0);
                acc0 = __builtin_amdgcn_mfma_f32_16x16x32_bf16(a_hi[it][0], b_lo[0], acc0, 0, 0, 0);
                acc1 = __builtin_amdgcn_mfma_f32_16x16x32_bf16(a_hi[it][1], b_lo[1], acc1, 0, 0, 0);
                acc0 = __builtin_amdgcn_mfma_f32_16x16x32_bf16(a_hi[it][0], b_hi[0], acc0, 0, 0, 0);
                acc1 = __builtin_amdgcn_mfma_f32_16x16x32_bf16(a_hi[it][1], b_hi[1], acc1, 0, 0, 0);

#pragma unroll
                for (int r = 0; r < 4; r++) {
                    int idx = it * 4 + r;
                    float D = acc0[r] + acc1[r];                  // dot - (sqi+sqj)/2
                    float u = fmaxf(D * rcpi[idx] * mj.z, EPSF);
                    float srt = __builtin_amdgcn_sqrtf(fmaf(u, u, u + u));
                    float opu = 1.0f + u;
                    float st = opu - srt;                         // exp(-d)
                    float l2 = __builtin_amdgcn_logf(opu + srt);  // d / ln2
                    float tv = (mj.w == labi[idx]) ? l2 : 0.0f;
                    Sx[idx] += st;
                    Tx[idx] += tv;
                    pS += st; pT += tv;
                }
            }

            if (full) {
                // sum the 4 quads -> full 32-row partial for column jg
                pS += __shfl_xor(pS, 16); pS += __shfl_xor(pS, 32);
                pT += __shfl_xor(pT, 16); pT += __shfl_xor(pT, 32);
                if (quad == 0) {
                    int c = t * 16 + l15;
                    slabS[wave][c] += pS;
                    slabT[wave][c] += pT;
                }
            }
        }

        // i-side: reduce across 16 j-columns (lanes within a quad share rows)
#pragma unroll
        for (int r = 0; r < 8; r++) {
#pragma unroll
            for (int m = 1; m < 16; m <<= 1) {
                Sx[r] += __shfl_xor(Sx[r], m);
                Tx[r] += __shfl_xor(Tx[r], m);
            }
        }
        if (l15 == 0) {
#pragma unroll
            for (int it = 0; it < 2; it++)
#pragma unroll
                for (int r = 0; r < 4; r++) {
                    int row = i0 + it * 16 + quad * 4 + r;
                    atomicAdd(&Sarr[row], Sx[it * 4 + r]);
                    atomicAdd(&Tarr[row], Tx[it * 4 + r]);
                }
        }

        // j-side: flush per-wave slabs (block-uniform branch)
        if (full) {
            __syncthreads();
            float s = slabS[0][tid] + slabS[1][tid] + slabS[2][tid] + slabS[3][tid];
            float tt = slabT[0][tid] + slabT[1][tid] + slabT[2][tid] + slabT[3][tid];
            atomicAdd(&Sarr[j0 + tid], s);
            atomicAdd(&Tarr[j0 + tid], tt);
        }
        __syncthreads();   // protect slab & curTile reuse across loop iterations
    }
}

// ---- kernel 3: finalize, 32 parallel blocks ---------------------------------
__global__ void __launch_bounds__(256) finalize_kernel(
        const float* __restrict__ S, const float* __restrict__ T,
        const int* __restrict__ labels, float* __restrict__ out) {
    __shared__ int hist[16][16];
    __shared__ float cntf[16];
    __shared__ float red[256];
    int tid = threadIdx.x;
    hist[tid >> 4][tid & 15] = 0;
    __syncthreads();
    int rep = tid & 15;
    for (int i = tid; i < NPTS; i += 256)
        atomicAdd(&hist[rep][labels[i]], 1);
    __syncthreads();
    if (tid < 16) {
        int s = 0;
#pragma unroll
        for (int k = 0; k < 16; k++) s += hist[k][tid];
        cntf[tid] = (float)(s - 1);
    }
    __syncthreads();

    float s0 = __builtin_amdgcn_sqrtf(EPSF * (2.0f + EPSF));
    float st0 = 1.0f + EPSF - s0;                         // self exp(-d) term
    float l20 = __builtin_amdgcn_logf(1.0f + EPSF + s0);  // self log2 term
    int i = blockIdx.x * 256 + tid;
    float loss = __logf(S[i] - st0) + (T[i] - l20) * LN2F / cntf[labels[i]];
    red[tid] = loss;
    __syncthreads();
    for (int s = 128; s > 0; s >>= 1) {
        if (tid < s) red[tid] += red[tid + s];
        __syncthreads();
    }
    if (tid == 0) atomicAdd(out, red[0]);
}

extern "C" void kernel_launch(void* const* d_in, const int* in_sizes, int n_in,
                              void* d_out, int out_size, void* d_ws, size_t ws_size,
                              hipStream_t stream) {
    const float* x = (const float*)d_in[0];
    const int* labels = (const int*)d_in[1];

    u16* hi = (u16*)d_ws;                 // NPTS*DIM u16
    u16* lo = hi + NPTS * DIM;            // NPTS*DIM u16
    float4* meta = (float4*)(lo + NPTS * DIM);
    float* S = (float*)(meta + NPTS);
    float* T = S + NPTS;
    int* ctr = (int*)(T + NPTS);

    prep_kernel<<<(NPTS * 8) / 256, 256, 0, stream>>>(x, labels, hi, lo, meta, S, T, (float*)d_out, ctr);

    pair_mfma<<<PERSISTENT, 256, 0, stream>>>(hi, lo, meta, S, T, ctr);

    finalize_kernel<<<NPTS / 256, 256, 0, stream>>>(S, T, labels, (float*)d_out);
}